// Round 3
// baseline (1410.964 us; speedup 1.0000x reference)
//
#include <hip/hip_runtime.h>

#define NGRIDF 4194304.0f      // 2^22
#define NSEG 8                 // 8 segments of 2.1 MB -> fits 4 MB per-XCD L2
#define PTS 64                 // points per thread (exact single-cohort residency)
#define F4S 16                 // float4 groups per thread
#define LDS_FLOATS 40          // 40 x-values in LDS (40 KB/block -> 4 blocks/CU)
#define REG_FLOATS 24          // remaining 24 x-values in VGPRs

// Single-cohort segment sweep:
//  - grid is exactly resident (1024 blocks * 256 thr = 262144 threads,
//    4 waves/SIMD at <=128 VGPR, 40KB LDS -> 4 blocks/CU)
//  - each thread owns 64 points: x staged once (LDS+regs), acc[64] in VGPRs
//  - 8 passes over c-segments; per pass only in-segment points gather,
//    so the whole chip's gathers stay inside a 2.1 MB L2-resident window.
__global__ __launch_bounds__(256, 4) void spline_cohort_kernel(
    const float* __restrict__ x, const float* __restrict__ c,
    float* __restrict__ out)
{
    __shared__ float xls[LDS_FLOATS][256];   // transposed: conflict-free per-lane reads
    const int t = threadIdx.x;
    const int blockBase = blockIdx.x * (F4S * 256);   // in float4 units
    const float4* __restrict__ x4 = reinterpret_cast<const float4*>(x);
    float4* __restrict__ o4 = reinterpret_cast<float4*>(out);

    float xr[REG_FLOATS];

    // Stage x: coalesced float4 loads, first 10 groups -> LDS, last 6 -> regs
    #pragma unroll
    for (int f = 0; f < F4S; ++f) {
        float4 v = x4[blockBase + f * 256 + t];
        if (f < LDS_FLOATS / 4) {
            xls[f * 4 + 0][t] = v.x;
            xls[f * 4 + 1][t] = v.y;
            xls[f * 4 + 2][t] = v.z;
            xls[f * 4 + 3][t] = v.w;
        } else {
            int r0 = (f - LDS_FLOATS / 4) * 4;
            xr[r0 + 0] = v.x;
            xr[r0 + 1] = v.y;
            xr[r0 + 2] = v.z;
            xr[r0 + 3] = v.w;
        }
    }
    __syncthreads();

    float acc[PTS];
    #pragma unroll
    for (int i = 0; i < PTS; ++i) acc[i] = 0.0f;

    // Sweep the 8 coefficient segments; all waves are resident simultaneously,
    // so the active 2.1 MB window is L2-resident on every XCD.
    for (int seg = 0; seg < NSEG; ++seg) {
        const float lo = (float)seg * 0.125f;   // exact (2^-3 multiples)
        const float hi = lo + 0.125f;
        #pragma unroll
        for (int idx = 0; idx < PTS; ++idx) {
            float xs = (idx < LDS_FLOATS) ? xls[idx][t] : xr[idx - LDS_FLOATS];
            if (xs >= lo && xs < hi) {
                // s = x * 2^22 is exact; (s+2) carries the reference's rounding
                // quirk; all following subtractions are exact, so g/fr match the
                // reference's t-values bitwise.
                float s   = xs * NGRIDF;
                int   b   = (int)s;                 // floor (s >= 0)
                float sp2 = s + 2.0f;
                float g   = sp2 - (float)(b + 1);   // in [1,2)
                float fr  = g - 1.0f;               // frac, in [0,1)
                float om  = 1.0f - fr;
                float fr2 = fr * fr, fr3 = fr2 * fr;
                float om2 = om * om, om3 = om2 * om;
                // t0=fr+1 -> (2-t0)^3 = om^3 ; t1=fr -> inner(fr)
                // t2=fr-1 -> inner(om)        ; t3=fr-2 -> (2-|t3|)^3 = fr^3
                float w1 = fmaf(3.0f, fr3, fmaf(-6.0f, fr2, 4.0f));
                float w2 = fmaf(3.0f, om3, fmaf(-6.0f, om2, 4.0f));
                const float* cp = c + b;
                float rr = om3 * cp[0];
                rr = fmaf(w1,  cp[1], rr);
                rr = fmaf(w2,  cp[2], rr);
                rr = fmaf(fr3, cp[3], rr);
                acc[idx] = rr;                      // each point hits exactly one seg
            }
        }
    }

    // Coalesced float4 write-back
    #pragma unroll
    for (int f = 0; f < F4S; ++f) {
        float4 v = make_float4(acc[f * 4 + 0], acc[f * 4 + 1],
                               acc[f * 4 + 2], acc[f * 4 + 3]);
        o4[blockBase + f * 256 + t] = v;
    }
}

extern "C" void kernel_launch(void* const* d_in, const int* in_sizes, int n_in,
                              void* d_out, int out_size, void* d_ws, size_t ws_size,
                              hipStream_t stream) {
    const float* x = (const float*)d_in[0];
    const float* c = (const float*)d_in[1];
    float* out = (float*)d_out;
    int n = in_sizes[0];                 // 16777216
    int grid = n / (256 * PTS);          // 1024 blocks -> exactly resident

    spline_cohort_kernel<<<grid, 256, 0, stream>>>(x, c, out);
}

// Round 4
// 144.472 us; speedup vs baseline: 9.7664x; 9.7664x over previous
//
#include <hip/hip_runtime.h>

#define NGRID  4194304         // 2^22
#define NGRIDF 4194304.0f
#define NSEG 8                 // 2.1 MB segments -> L2-resident window per XCD
#define PTS 64                 // points per thread
#define BIAS 64.0f             // "done" encoding: store -(result+BIAS) < 0

// Process one point in-place if it falls in [lo, hi). On process, the
// register is overwritten with -(result+BIAS) which is always negative,
// so all later segment tests (lo >= 0) fail: each point computed once.
__device__ __forceinline__ void proc(float& p, float lo, float hi,
                                     const float* __restrict__ c) {
    if (p >= lo && p < hi) {
        // s = x * 2^22 exact; sp2 = s+2 carries the reference's rounding;
        // all later subtractions exact -> bitwise-identical t values.
        float s   = p * NGRIDF;
        int   b   = (int)s;                    // floor, s >= 0
        b = min(b, NGRID - 1);                 // memory-safety only (x < 1)
        float sp2 = s + 2.0f;
        float g   = sp2 - (float)(b + 1);      // in [1,2)
        float fr  = g - 1.0f;                  // exact (Sterbenz)
        float om  = 1.0f - fr;
        float fr2 = fr * fr, fr3 = fr2 * fr;
        float om2 = om * om,  om3 = om2 * om;
        float w1 = fmaf(3.0f, fr3, fmaf(-6.0f, fr2, 4.0f));
        float w2 = fmaf(3.0f, om3, fmaf(-6.0f, om2, 4.0f));
        const float* cp = c + b;
        float rr = om3 * cp[0];
        rr = fmaf(w1,  cp[1], rr);
        rr = fmaf(w2,  cp[2], rr);
        rr = fmaf(fr3, cp[3], rr);
        p = -(rr + BIAS);
    }
}

// Single-cohort persistent sweep: 1024 blocks * 256 thr = 262144 threads,
// all resident (4 blocks/CU, 0 LDS, <=128 VGPR). Each thread owns 64 points
// held in 16 explicit float4 registers (x overwritten by result in place).
__global__ __launch_bounds__(256, 4) void spline_resident_kernel(
    const float* __restrict__ x, const float* __restrict__ c,
    float* __restrict__ out)
{
    const int t = threadIdx.x;
    const int blockBase = blockIdx.x * (16 * 256);   // in float4 units
    const float4* __restrict__ x4 = reinterpret_cast<const float4*>(x);
    float4* __restrict__ o4 = reinterpret_cast<float4*>(out);

#define LD(i) float4 v##i = x4[blockBase + (i) * 256 + t];
    LD(0)  LD(1)  LD(2)  LD(3)  LD(4)  LD(5)  LD(6)  LD(7)
    LD(8)  LD(9)  LD(10) LD(11) LD(12) LD(13) LD(14) LD(15)
#undef LD

#define P4(i) proc(v##i.x, lo, hi, c); proc(v##i.y, lo, hi, c); \
              proc(v##i.z, lo, hi, c); proc(v##i.w, lo, hi, c);
    #pragma unroll 1
    for (int seg = 0; seg < NSEG; ++seg) {
        const float lo = (float)seg * 0.125f;   // exact
        const float hi = lo + 0.125f;
        P4(0)  P4(1)  P4(2)  P4(3)  P4(4)  P4(5)  P4(6)  P4(7)
        P4(8)  P4(9)  P4(10) P4(11) P4(12) P4(13) P4(14) P4(15)
    }
#undef P4

#define ST(i) o4[blockBase + (i) * 256 + t] = \
        make_float4(-v##i.x - BIAS, -v##i.y - BIAS, -v##i.z - BIAS, -v##i.w - BIAS);
    ST(0)  ST(1)  ST(2)  ST(3)  ST(4)  ST(5)  ST(6)  ST(7)
    ST(8)  ST(9)  ST(10) ST(11) ST(12) ST(13) ST(14) ST(15)
#undef ST
}

extern "C" void kernel_launch(void* const* d_in, const int* in_sizes, int n_in,
                              void* d_out, int out_size, void* d_ws, size_t ws_size,
                              hipStream_t stream) {
    const float* x = (const float*)d_in[0];
    const float* c = (const float*)d_in[1];
    float* out = (float*)d_out;
    int n = in_sizes[0];                 // 16777216
    int grid = n / (256 * PTS);          // 1024 blocks -> exactly resident

    spline_resident_kernel<<<grid, 256, 0, stream>>>(x, c, out);
}

// Round 5
// 105.918 us; speedup vs baseline: 13.3213x; 1.3640x over previous
//
#include <hip/hip_runtime.h>

#define NGRIDF 4194304.0f      // 2^22
#define NSEG 5                 // 3.36 MB windows -> resident in 4 MB per-XCD L2
#define PTS 32                 // points per thread
#define BIAS 64.0f             // done-marker: store -(BIAS+rr) < 0

// Unaligned-capable 16B vector load (gfx9+ supports align-4 dwordx4)
typedef float f32x4u __attribute__((ext_vector_type(4), aligned(4)));

// Process point in place if p >= lo (descending sweep). Done points are
// negative so they fail every later test. Segment boundaries don't affect
// results -- only exactly-once processing matters, which the marker ensures.
__device__ __forceinline__ void proc(float& p, float lo,
                                     const float* __restrict__ c) {
    if (p >= lo) {
        // s = x*2^22 exact; sp2 = s+2 replicates the reference's rounding;
        // all later subtractions exact -> bitwise-identical basis arguments.
        float s   = p * NGRIDF;
        int   b   = (int)s;                    // floor; b <= 2^22-1 provably
        float sp2 = s + 2.0f;
        float g   = sp2 - (float)(b + 1);      // in [1,2)
        float fr  = g - 1.0f;                  // exact (Sterbenz)
        float om  = 1.0f - fr;
        float fr2 = fr * fr, fr3 = fr2 * fr;
        float om2 = om * om,  om3 = om2 * om;
        float w1 = fmaf(3.0f, fr3, fmaf(-6.0f, fr2, 4.0f));
        float w2 = fmaf(3.0f, om3, fmaf(-6.0f, om2, 4.0f));
        f32x4u cv = *reinterpret_cast<const f32x4u*>(c + b);  // 1x dwordx4
        float rr = om3 * cv.x;
        rr = fmaf(w1,  cv.y, rr);
        rr = fmaf(w2,  cv.z, rr);
        rr = fmaf(fr3, cv.w, rr);
        p = -BIAS - rr;                        // single-op encode, always < 0
    }
}

// Single-cohort persistent sweep at FULL occupancy:
// 2048 blocks * 256 thr = 524288 threads = 8 blocks/CU * 4 waves = 32 waves/CU
// (requires VGPR <= 64: 8 float4 of state, zero LDS, lean body).
__global__ __launch_bounds__(256, 8) void spline_resident32_kernel(
    const float* __restrict__ x, const float* __restrict__ c,
    float* __restrict__ out)
{
    const int t = threadIdx.x;
    const int blockBase = blockIdx.x * (8 * 256);   // in float4 units
    const float4* __restrict__ x4 = reinterpret_cast<const float4*>(x);
    float4* __restrict__ o4 = reinterpret_cast<float4*>(out);

#define LD(i) float4 v##i = x4[blockBase + (i) * 256 + t];
    LD(0) LD(1) LD(2) LD(3) LD(4) LD(5) LD(6) LD(7)
#undef LD

#define P4(i) proc(v##i.x, lo, c); proc(v##i.y, lo, c); \
              proc(v##i.z, lo, c); proc(v##i.w, lo, c);
    #pragma unroll 1
    for (int seg = NSEG - 1; seg >= 0; --seg) {     // descending: 1 cmp/test
        const float lo = (float)seg * 0.2f;         // last pass lo == 0.0f
        P4(0) P4(1) P4(2) P4(3) P4(4) P4(5) P4(6) P4(7)
    }
#undef P4

    // Decode: stored = -(BIAS+rr); out = -stored - BIAS = rr (Sterbenz-exact
    // in the subtract; only the encode rounding ~7.6e-6 remains).
#define ST(i) o4[blockBase + (i) * 256 + t] = \
        make_float4(-v##i.x - BIAS, -v##i.y - BIAS, -v##i.z - BIAS, -v##i.w - BIAS);
    ST(0) ST(1) ST(2) ST(3) ST(4) ST(5) ST(6) ST(7)
#undef ST
}

extern "C" void kernel_launch(void* const* d_in, const int* in_sizes, int n_in,
                              void* d_out, int out_size, void* d_ws, size_t ws_size,
                              hipStream_t stream) {
    const float* x = (const float*)d_in[0];
    const float* c = (const float*)d_in[1];
    float* out = (float*)d_out;
    int n = in_sizes[0];                 // 16777216
    int grid = n / (256 * PTS);          // 2048 blocks -> exactly resident

    spline_resident32_kernel<<<grid, 256, 0, stream>>>(x, c, out);
}